// Round 1
// 433.186 us; speedup vs baseline: 1.0622x; 1.0622x over previous
//
#include <hip/hip_runtime.h>

// KVGather, source-major formulation.
// out[b,p,t,:,:] = kv[b, r_idx[b,p,t], :, :]
// B=4, P2=64, TOPK=16, W2=49, C_KV=512
//
// Output: 411 MB (mandatory writes). kv: 25.7 MB.
// Previous dest-major kernel read kv ~16x (up to 411 MB of reads) and relied
// on L2/L3 to absorb it -- but per-XCD L2 (4 MiB) < per-batch working set
// (6.3 MiB), and the NT-store stream + harness poison fill evict L3.
// Measured ~200 us ~= 822 MB @ 4.1 TB/s mixed R/W.
//
// This version inverts the gather: one block per (b, src_region, chunk).
// Each block builds the destination list for its source region (scan of
// 1024 ints, LDS-compacted), then reads each float4 of its chunk ONCE and
// fans it out to all n destinations with non-temporal stores.
// HBM reads: ~26 MB. Writes: 411 MB. Roofline ~= 70 us.

constexpr int B    = 4;
constexpr int P2   = 64;
constexpr int TOPK = 16;
constexpr int W2   = 49;
constexpr int C_KV = 512;
constexpr int REGION  = W2 * C_KV;        // 25088 floats per region
constexpr int REGION4 = REGION / 4;       // 6272 float4 per region
constexpr int PT      = P2 * TOPK;        // 1024 dest slots per batch
constexpr int CHUNKS  = 8;                // chunk-blocks per source region
constexpr int CHUNK4  = REGION4 / CHUNKS; // 784 float4 per chunk (exact)
constexpr int TPB     = 256;
constexpr int NBLOCKS = B * P2 * CHUNKS;  // 2048 blocks

// clang ext-vector: accepted by __builtin_nontemporal_store
typedef float floatx4 __attribute__((ext_vector_type(4)));

__global__ __launch_bounds__(TPB) void kvgather_srcmajor(
    const int* __restrict__ r_idx,   // (B, P2, TOPK) flat, int32
    const float* __restrict__ kv,    // (B, P2, W2, C_KV) flat
    float* __restrict__ out)         // (B, P2, TOPK, W2, C_KV) flat
{
    const int blk = blockIdx.x;
    const int c   = blk & (CHUNKS - 1);  // chunk within region
    const int bs  = blk >> 3;            // b*P2 + src
    const int b   = bs >> 6;             // / P2
    const int src = bs & (P2 - 1);

    __shared__ int s_cnt;
    __shared__ int s_base4[PT];          // dest offsets in float4 units

    if (threadIdx.x == 0) s_cnt = 0;
    __syncthreads();

    // Invert r_idx for this (b, src): each thread checks 4 of the 1024
    // dest slots of batch b; matches are compacted into LDS.
    {
        const int4 rv = ((const int4*)(r_idx + b * PT))[threadIdx.x];
        const int vals[4] = { rv.x, rv.y, rv.z, rv.w };
        #pragma unroll
        for (int j = 0; j < 4; ++j) {
            if (vals[j] == src) {
                const int pos = atomicAdd(&s_cnt, 1);
                // (global dest region index) * REGION4; max ~25.7M, fits int32
                s_base4[pos] = (b * PT + threadIdx.x * 4 + j) * REGION4;
            }
        }
    }
    __syncthreads();
    const int n = s_cnt;
    if (n == 0) return;                  // P(no dest) ~ e^-16, but be safe

    const floatx4* __restrict__ s4 = (const floatx4*)kv + (size_t)bs * REGION4;
    floatx4* __restrict__ o4 = (floatx4*)out;

    // Read each float4 of this chunk once; fan out to all n destinations.
    // Per store instruction a wave writes 1 KB contiguous -- fully coalesced.
    // LDS broadcast reads of s_base4[k] are issue-side noise vs HBM write BW.
    const int i0 = c * CHUNK4;
    const int i1 = i0 + CHUNK4;
    for (int i = i0 + threadIdx.x; i < i1; i += TPB) {
        const floatx4 v = s4[i];
        for (int k = 0; k < n; ++k) {
            __builtin_nontemporal_store(v, o4 + (size_t)(s_base4[k] + i));
        }
    }
}

extern "C" void kernel_launch(void* const* d_in, const int* in_sizes, int n_in,
                              void* d_out, int out_size, void* d_ws, size_t ws_size,
                              hipStream_t stream) {
    const int*   r_idx = (const int*)d_in[0];
    const float* kv    = (const float*)d_in[1];
    float*       out   = (float*)d_out;

    kvgather_srcmajor<<<NBLOCKS, TPB, 0, stream>>>(r_idx, kv, out);
}

// Round 2
// 428.532 us; speedup vs baseline: 1.0737x; 1.0109x over previous
//
#include <hip/hip_runtime.h>

// KVGather, source-major + register-staged + CACHED (non-NT) stores.
// out[b,p,t,:,:] = kv[b, r_idx[b,p,t], :, :]
// B=4, P2=64, TOPK=16, W2=49, C_KV=512
//
// Evidence trail:
//  - dest-major + NT stores:  ~202 us  (~2.0 TB/s effective write BW)
//  - src-major  + NT stores:  ~175 us  (~2.35 TB/s, reads eliminated)
//  - harness fillBuffer (plain stores): 6.35 TB/s on the same buffer
// => the NT store path itself caps at ~2.3 TB/s on gfx950. Drop it.
//    L2/L3 pollution is a non-issue: read working set is 26 MB vs 256 MB L3.
//
// Structure: one block per (b, src_region, chunk). Invert r_idx into LDS,
// stage the 12.5 KB chunk in registers, then per-dest contiguous burst
// writes (k-outer), dest base read from LDS once per k.

constexpr int B    = 4;
constexpr int P2   = 64;
constexpr int TOPK = 16;
constexpr int W2   = 49;
constexpr int C_KV = 512;
constexpr int REGION4 = W2 * C_KV / 4;     // 6272 float4 per region
constexpr int PT      = P2 * TOPK;         // 1024 dest slots per batch
constexpr int CHUNKS  = 8;                 // chunk-blocks per source region
constexpr int CHUNK4  = REGION4 / CHUNKS;  // 784 float4 per chunk (exact)
constexpr int TPB     = 256;
constexpr int NBLOCKS = B * P2 * CHUNKS;   // 2048 blocks = 8/CU, full occupancy

typedef float floatx4 __attribute__((ext_vector_type(4)));

__global__ __launch_bounds__(TPB) void kvgather_srcmajor_reg(
    const int* __restrict__ r_idx,   // (B, P2, TOPK) flat, int32
    const float* __restrict__ kv,    // (B, P2, W2, C_KV) flat
    float* __restrict__ out)         // (B, P2, TOPK, W2, C_KV) flat
{
    const int blk = blockIdx.x;
    const int c   = blk & (CHUNKS - 1);  // chunk within region
    const int bs  = blk >> 3;            // b*P2 + src
    const int b   = bs >> 6;             // / P2
    const int src = bs & (P2 - 1);
    const int t   = threadIdx.x;

    __shared__ int s_cnt;
    __shared__ int s_base4[PT];          // dest offsets in float4 units

    if (t == 0) s_cnt = 0;
    __syncthreads();

    // Invert r_idx for this (b, src): each thread checks 4 of the 1024
    // dest slots of batch b; matches are compacted into LDS.
    {
        const int4 rv = ((const int4*)(r_idx + b * PT))[t];
        const int vals[4] = { rv.x, rv.y, rv.z, rv.w };
        #pragma unroll
        for (int j = 0; j < 4; ++j) {
            if (vals[j] == src) {
                const int pos = atomicAdd(&s_cnt, 1);
                // (global dest region idx) * REGION4; max ~25.7M, fits int32
                s_base4[pos] = (b * PT + t * 4 + j) * REGION4;
            }
        }
    }
    __syncthreads();
    const int n = s_cnt;
    if (n == 0) return;                  // P ~ e^-16, but be safe

    // Stage this block's chunk (784 float4 = 12.5 KB) in registers:
    // 3 full rounds + 16-thread tail. One vmcnt wait total.
    const floatx4* __restrict__ s4 =
        (const floatx4*)kv + (size_t)bs * REGION4 + c * CHUNK4;
    const floatx4 v0 = s4[t];
    const floatx4 v1 = s4[t + 256];
    const floatx4 v2 = s4[t + 512];
    floatx4 v3 = {};
    if (t < 16) v3 = s4[t + 768];

    // Per dest: one contiguous 12.5 KB burst (1 KB per wave per store instr).
    floatx4* __restrict__ o4 = (floatx4*)out + c * CHUNK4;
    for (int k = 0; k < n; ++k) {
        floatx4* __restrict__ d = o4 + s_base4[k];
        d[t]       = v0;
        d[t + 256] = v1;
        d[t + 512] = v2;
        if (t < 16) d[t + 768] = v3;
    }
}

extern "C" void kernel_launch(void* const* d_in, const int* in_sizes, int n_in,
                              void* d_out, int out_size, void* d_ws, size_t ws_size,
                              hipStream_t stream) {
    const int*   r_idx = (const int*)d_in[0];
    const float* kv    = (const float*)d_in[1];
    float*       out   = (float*)d_out;

    kvgather_srcmajor_reg<<<NBLOCKS, TPB, 0, stream>>>(r_idx, kv, out);
}